// Round 8
// baseline (11998.703 us; speedup 1.0000x reference)
//
#include <hip/hip_runtime.h>
#include <stdint.h>

#define BB   64
#define TT   512
#define KIN  256
#define HH   512
#define NBLK 64      // j-slices (8 columns of H each)
#define NJ   8

typedef short bf16x8 __attribute__((ext_vector_type(8)));
typedef float f32x4  __attribute__((ext_vector_type(4)));
typedef unsigned long long u64;

union U16x8 { unsigned short s[8]; bf16x8 v; };
union FU    { float f; unsigned u; };

__device__ u64 g_hbuf[2*(size_t)BB*HH];   // 512 KB fallback h exchange buffer

__device__ __forceinline__ unsigned short f2bf(float f){
  FU v; v.f = f;
  unsigned r = v.u + 0x7fffu + ((v.u >> 16) & 1u);   // RNE
  return (unsigned short)(r >> 16);
}
__device__ __forceinline__ float bf2f(unsigned short s){
  FU v; v.u = ((unsigned)s) << 16; return v.f;
}
__device__ __forceinline__ bf16x8 zfrag(){
  U16x8 z;
  #pragma unroll
  for(int i=0;i<8;i++) z.s[i]=0;
  return z.v;
}
// 8 consecutive f32 -> split bf16 hi/lo fragments
__device__ __forceinline__ void split8(const float* p, bf16x8& hi, bf16x8& lo){
  float4 a = ((const float4*)p)[0];
  float4 b = ((const float4*)p)[1];
  float f[8] = {a.x,a.y,a.z,a.w,b.x,b.y,b.z,b.w};
  U16x8 h,l;
  #pragma unroll
  for(int i=0;i<8;i++){
    unsigned short hb = f2bf(f[i]);
    l.s[i] = f2bf(f[i] - bf2f(hb));
    h.s[i] = hb;
  }
  hi = h.v; lo = l.v;
}
// 4 uint4 = 8 u64 {data,seq}; data words at .x/.z -> hi/lo fragments (k0..k7)
__device__ __forceinline__ void unpack4(uint4 A, uint4 B, uint4 C, uint4 D,
                                        bf16x8& hi, bf16x8& lo){
  unsigned wv[8] = {A.x,A.z,B.x,B.z,C.x,C.z,D.x,D.z};
  U16x8 h,l;
  #pragma unroll
  for(int j=0;j<8;j++){
    h.s[j] = (unsigned short)(wv[j] >> 16);
    l.s[j] = (unsigned short)(wv[j] & 0xffffu);
  }
  hi = h.v; lo = l.v;
}

#define MFMA __builtin_amdgcn_mfma_f32_16x16x32_bf16

// SELF-CONTAINED: 16 coherent dwordx4 loads + vmcnt(0) drain in ONE asm block.
// Outputs are architecturally ready at exit -> no in-flight-register hazard.
#define LD16W(G0,G1,G2,G3,G4,G5,G6,G7,G8,G9,Ga,Gb,Gc,Gd,Ge,Gf, BASE) \
  asm volatile( \
    "global_load_dwordx4 %0, %16, off sc1\n\t" \
    "global_load_dwordx4 %1, %16, off offset:16 sc1\n\t" \
    "global_load_dwordx4 %2, %16, off offset:32 sc1\n\t" \
    "global_load_dwordx4 %3, %16, off offset:48 sc1\n\t" \
    "global_load_dwordx4 %4, %16, off offset:256 sc1\n\t" \
    "global_load_dwordx4 %5, %16, off offset:272 sc1\n\t" \
    "global_load_dwordx4 %6, %16, off offset:288 sc1\n\t" \
    "global_load_dwordx4 %7, %16, off offset:304 sc1\n\t" \
    "global_load_dwordx4 %8, %16, off offset:512 sc1\n\t" \
    "global_load_dwordx4 %9, %16, off offset:528 sc1\n\t" \
    "global_load_dwordx4 %10, %16, off offset:544 sc1\n\t" \
    "global_load_dwordx4 %11, %16, off offset:560 sc1\n\t" \
    "global_load_dwordx4 %12, %16, off offset:768 sc1\n\t" \
    "global_load_dwordx4 %13, %16, off offset:784 sc1\n\t" \
    "global_load_dwordx4 %14, %16, off offset:800 sc1\n\t" \
    "global_load_dwordx4 %15, %16, off offset:816 sc1\n\t" \
    "s_waitcnt vmcnt(0)" \
    : "=&v"(G0),"=&v"(G1),"=&v"(G2),"=&v"(G3),"=&v"(G4),"=&v"(G5),"=&v"(G6),"=&v"(G7), \
      "=&v"(G8),"=&v"(G9),"=&v"(Ga),"=&v"(Gb),"=&v"(Gc),"=&v"(Gd),"=&v"(Ge),"=&v"(Gf) \
    : "v"(BASE) : "memory")

#define CHK8(G0,G1,G2,G3,G4,G5,G6,G7) \
  ((G0.y^rtag)|(G0.w^rtag)|(G1.y^rtag)|(G1.w^rtag)|(G2.y^rtag)|(G2.w^rtag)| \
   (G3.y^rtag)|(G3.w^rtag)|(G4.y^rtag)|(G4.w^rtag)|(G5.y^rtag)|(G5.w^rtag)| \
   (G6.y^rtag)|(G6.w^rtag)|(G7.y^rtag)|(G7.w^rtag))

#define CONSUME(Q0,Q1,Q2,Q3,Q4,Q5,Q6,Q7,Q8,Q9,Qa,Qb,Qc,Qd,Qe,Qf, MI) do{ \
    bf16x8 ah, al; \
    unpack4(Q0,Q1,Q2,Q3,ah,al); \
    _Pragma("unroll") \
    for(int nt=0;nt<2;nt++){ Ch[MI][nt]=MFMA(ah,BUhi[nt][0],Ch[MI][nt],0,0,0); Ch[MI][nt]=MFMA(ah,BUlo[nt][0],Ch[MI][nt],0,0,0); Ch[MI][nt]=MFMA(al,BUhi[nt][0],Ch[MI][nt],0,0,0); } \
    unpack4(Q4,Q5,Q6,Q7,ah,al); \
    _Pragma("unroll") \
    for(int nt=0;nt<2;nt++){ Ch[MI][nt]=MFMA(ah,BUhi[nt][1],Ch[MI][nt],0,0,0); Ch[MI][nt]=MFMA(ah,BUlo[nt][1],Ch[MI][nt],0,0,0); Ch[MI][nt]=MFMA(al,BUhi[nt][1],Ch[MI][nt],0,0,0); } \
    unpack4(Q8,Q9,Qa,Qb,ah,al); \
    _Pragma("unroll") \
    for(int nt=0;nt<2;nt++){ Ch[MI][nt]=MFMA(ah,BUhi[nt][2],Ch[MI][nt],0,0,0); Ch[MI][nt]=MFMA(ah,BUlo[nt][2],Ch[MI][nt],0,0,0); Ch[MI][nt]=MFMA(al,BUhi[nt][2],Ch[MI][nt],0,0,0); } \
    unpack4(Qc,Qd,Qe,Qf,ah,al); \
    _Pragma("unroll") \
    for(int nt=0;nt<2;nt++){ Ch[MI][nt]=MFMA(ah,BUhi[nt][3],Ch[MI][nt],0,0,0); Ch[MI][nt]=MFMA(ah,BUlo[nt][3],Ch[MI][nt],0,0,0); Ch[MI][nt]=MFMA(al,BUhi[nt][3],Ch[MI][nt],0,0,0); } \
  }while(0)

__global__ __launch_bounds__(512, 2) void gru_scan(
    const float* __restrict__ x,  const float* __restrict__ Wm,
    const float* __restrict__ bW, const float* __restrict__ Um,
    const float* __restrict__ bU, float* __restrict__ out,
    u64* __restrict__ hbuf)
{
  __shared__ f32x4 red [4][4][2][64];   // [q][mt][nt][lane] h-gate reduce (32 KB)
  __shared__ f32x4 red2[4][4][2][64];   // xg reduce (32 KB)

  const int tid  = threadIdx.x;
  const int u    = tid >> 6;        // wave 0..7
  const int q    = u >> 1;          // k-quarter
  const int m2   = u & 1;           // mt-pair: mt in {2*m2, 2*m2+1}
  const int lane = tid & 63;
  const int col  = lane & 15;
  const int lg   = lane >> 4;
  const int j0   = blockIdx.x * NJ;

  // ---- persistent U/W fragments for k-quarter q (split bf16, registers) ----
  bf16x8 BUhi[2][4], BUlo[2][4], BWhi[2][2], BWlo[2][2];
  #pragma unroll
  for(int nt=0; nt<2; nt++){
    int rl    = nt*16 + col;          // local row 0..31 (24 valid)
    int valid = rl < 24;
    int g     = rl >> 3, jj = rl & 7;
    int grow  = g*HH + j0 + jj;       // row in [3H]
    #pragma unroll
    for(int ks=0; ks<4; ks++){
      int kb = q*128 + ks*32 + lg*8;
      if(valid) split8(Um + (size_t)grow*HH + kb, BUhi[nt][ks], BUlo[nt][ks]);
      else { BUhi[nt][ks]=zfrag(); BUlo[nt][ks]=zfrag(); }
    }
    #pragma unroll
    for(int ks=0; ks<2; ks++){
      int kb = q*64 + ks*32 + lg*8;
      if(valid) split8(Wm + (size_t)grow*KIN + kb, BWhi[nt][ks], BWlo[nt][ks]);
      else { BWhi[nt][ks]=zfrag(); BWlo[nt][ks]=zfrag(); }
    }
  }

  // ---- biases for this lane's gate rows (gate waves u<4) ----
  float bsum0, bwn, bun;
  {
    int r0 = (col < 8) ? (j0 + col) : (HH + j0 + col - 8);
    bsum0 = bW[r0] + bU[r0];
    int rn = 2*HH + j0 + (col & 7);
    bwn = bW[rn]; bun = bU[rn];
  }

  float hreg[4] = {0.f,0.f,0.f,0.f};

  // ---- xg partials + cross-wave reduce (red2); gate waves get sums ----
  auto compute_xg = [&](int tt, f32x4 (&dst)[2]){
    f32x4 Cx[2][2];
    #pragma unroll
    for(int mi=0;mi<2;mi++){ Cx[mi][0]=(f32x4){0,0,0,0}; Cx[mi][1]=(f32x4){0,0,0,0}; }
    #pragma unroll
    for(int mi=0; mi<2; mi++){
      int mt = 2*m2 + mi, b = mt*16 + col;
      #pragma unroll
      for(int ks=0; ks<2; ks++){
        int kb = q*64 + ks*32 + lg*8;
        bf16x8 ah, al; split8(x + ((size_t)b*TT + tt)*KIN + kb, ah, al);
        #pragma unroll
        for(int nt=0; nt<2; nt++){
          Cx[mi][nt] = MFMA(ah, BWhi[nt][ks], Cx[mi][nt], 0,0,0);
          Cx[mi][nt] = MFMA(ah, BWlo[nt][ks], Cx[mi][nt], 0,0,0);
          Cx[mi][nt] = MFMA(al, BWhi[nt][ks], Cx[mi][nt], 0,0,0);
        }
      }
    }
    #pragma unroll
    for(int mi=0;mi<2;mi++)
      #pragma unroll
      for(int nt=0;nt<2;nt++)
        red2[q][2*m2+mi][nt][lane] = Cx[mi][nt];
    __syncthreads();
    if(u < 4){
      #pragma unroll
      for(int nt=0; nt<2; nt++)
        dst[nt] = red2[0][u][nt][lane] + red2[1][u][nt][lane]
                + red2[2][u][nt][lane] + red2[3][u][nt][lane];
    }
  };

  // ---- one GRU cell: seq-tagged h exchange (self-validating loads) ----
  auto run_cell = [&](const u64* hb, u64* hw, unsigned rtag, unsigned wtag,
                      const f32x4 (&xgf)[2], float (&on)[4]){
    int b0 = (2*m2+0)*16 + col, b1 = (2*m2+1)*16 + col;
    const char* a0 = (const char*)(hb + (size_t)b0*HH + q*128 + lg*8);
    const char* a1 = (const char*)(hb + (size_t)b1*HH + q*128 + lg*8);
    uint4 g00,g01,g02,g03,g04,g05,g06,g07,g08,g09,g10,g11,g12,g13,g14,g15;

    f32x4 Ch[2][2];
    #pragma unroll
    for(int mi=0;mi<2;mi++){ Ch[mi][0]=(f32x4){0,0,0,0}; Ch[mi][1]=(f32x4){0,0,0,0}; }

    // row A: poll (each LD16W is load+drain, values ready at exit), then consume
    while(true){
      LD16W(g00,g01,g02,g03,g04,g05,g06,g07,g08,g09,g10,g11,g12,g13,g14,g15, a0);
      __builtin_amdgcn_sched_barrier(0);
      unsigned d = CHK8(g00,g01,g02,g03,g04,g05,g06,g07)
                 | CHK8(g08,g09,g10,g11,g12,g13,g14,g15);
      if(__all((int)(d == 0u))) break;
    }
    CONSUME(g00,g01,g02,g03,g04,g05,g06,g07,g08,g09,g10,g11,g12,g13,g14,g15, 0);

    // row B: same registers reused (row A fully consumed)
    while(true){
      LD16W(g00,g01,g02,g03,g04,g05,g06,g07,g08,g09,g10,g11,g12,g13,g14,g15, a1);
      __builtin_amdgcn_sched_barrier(0);
      unsigned d = CHK8(g00,g01,g02,g03,g04,g05,g06,g07)
                 | CHK8(g08,g09,g10,g11,g12,g13,g14,g15);
      if(__all((int)(d == 0u))) break;
    }
    CONSUME(g00,g01,g02,g03,g04,g05,g06,g07,g08,g09,g10,g11,g12,g13,g14,g15, 1);

    #pragma unroll
    for(int mi=0;mi<2;mi++)
      #pragma unroll
      for(int nt=0;nt<2;nt++)
        red[q][2*m2+mi][nt][lane] = Ch[mi][nt];
    __syncthreads();
    if(u < 4){
      const int w = u;
      f32x4 hgf[2];
      #pragma unroll
      for(int nt=0; nt<2; nt++)
        hgf[nt] = red[0][w][nt][lane] + red[1][w][nt][lane]
                + red[2][w][nt][lane] + red[3][w][nt][lane];
      float p0[4], p0s[4];
      #pragma unroll
      for(int r=0;r<4;r++) p0[r] = xgf[0][r] + hgf[0][r] + bsum0;
      #pragma unroll
      for(int r=0;r<4;r++) p0s[r] = __shfl_xor(p0[r], 8, 64);
      if(col < 8){
        #pragma unroll
        for(int r=0;r<4;r++){
          int b = w*16 + lg*4 + r;
          float rg = __builtin_amdgcn_rcpf(1.f + __expf(-p0[r]));
          float ug = __builtin_amdgcn_rcpf(1.f + __expf(-p0s[r]));
          float hn = hgf[1][r] + bun;
          float z  = xgf[1][r] + bwn + rg*hn;
          z = fminf(fmaxf(z, -15.f), 15.f);
          float e  = __expf(2.f*z);
          float nn = (e - 1.f) * __builtin_amdgcn_rcpf(e + 1.f);   // tanh(z)
          float hnew = ug*hreg[r] + (1.f - ug)*nn;
          hreg[r] = hnew;
          on[r]   = hnew;
          unsigned short h16 = f2bf(hnew);
          unsigned short l16 = f2bf(hnew - bf2f(h16));
          u64 pv = ((u64)wtag << 32) |
                   (u64)(((unsigned)h16 << 16) | (unsigned)l16);
          __hip_atomic_store(&hw[(size_t)b*HH + j0 + col], pv,
                             __ATOMIC_RELAXED, __HIP_MEMORY_SCOPE_AGENT);
        }
      }
    }
    // raw barrier: protects red WAR (ds_read uses completed before arrival)
    __builtin_amdgcn_s_barrier();
  };

  u64* hb0 = hbuf;
  u64* hb1 = hbuf + (size_t)BB*HH;

  f32x4 xgf[2] = {(f32x4){0,0,0,0},(f32x4){0,0,0,0}};
  f32x4 xgn[2] = {(f32x4){0,0,0,0},(f32x4){0,0,0,0}};
  float on0[4] = {0,0,0,0}, on1[4] = {0,0,0,0};
  compute_xg(0, xgf);

  for(int t=0; t<TT; t++){
    unsigned c0 = 2u*(unsigned)t;
    // layer 0: read buf0 (tag c0), write buf1 (tag c0+1)
    run_cell(hb0, hb1, c0, c0+1u, xgf, on0);
    if(u < 4 && col < 8){
      #pragma unroll
      for(int r=0;r<4;r++){
        int b = u*16 + lg*4 + r;
        out[((size_t)c0*BB + b)*HH + j0 + col] = on0[r];
      }
    }
    if(t+1 < TT) compute_xg(t+1, xgn);
    // layer 1: read buf1 (tag c0+1), write buf0 (tag c0+2)
    run_cell(hb1, hb0, c0+1u, c0+2u, xgf, on1);
    if(u < 4 && col < 8){
      #pragma unroll
      for(int r=0;r<4;r++){
        int b = u*16 + lg*4 + r;
        out[((size_t)(c0+1)*BB + b)*HH + j0 + col] = on1[r];
      }
    }
    xgf[0] = xgn[0]; xgf[1] = xgn[1];
  }
}

extern "C" void kernel_launch(void* const* d_in, const int* in_sizes, int n_in,
                              void* d_out, int out_size, void* d_ws, size_t ws_size,
                              hipStream_t stream) {
  const float* x  = (const float*)d_in[0];
  const float* Wm = (const float*)d_in[1];
  const float* bW = (const float*)d_in[2];
  const float* Um = (const float*)d_in[3];
  const float* bU = (const float*)d_in[4];
  float* out = (float*)d_out;

  // hbuf[2][64][512] u64 {tag | packed bf16 pair} = 512 KB.
  // Use d_ws only if provably large enough; else the __device__ global.
  const size_t need = 2*(size_t)BB*HH*sizeof(u64);
  u64* hbuf;
  if(ws_size >= need){
    hbuf = (u64*)d_ws;
  } else {
    void* p = nullptr;
    (void)hipGetSymbolAddress(&p, HIP_SYMBOL(g_hbuf));
    hbuf = (u64*)p;
  }
  (void)hipMemsetAsync(hbuf, 0, need, stream);   // tag 0 == "output of cell -1"

  gru_scan<<<NBLK, 512, 0, stream>>>(x, Wm, bW, Um, bU, out, hbuf);
}

// Round 9
// 7366.511 us; speedup vs baseline: 1.6288x; 1.6288x over previous
//
#include <hip/hip_runtime.h>
#include <stdint.h>

#define BB   64
#define TT   512
#define KIN  256
#define HH   512
#define NBLK 64      // j-slices (8 columns of H each)
#define NJ   8

typedef short bf16x8 __attribute__((ext_vector_type(8)));
typedef float f32x4  __attribute__((ext_vector_type(4)));

union U16x8 { unsigned short s[8]; bf16x8 v; };
union FU    { float f; unsigned u; };

__device__ __forceinline__ unsigned short f2bf(float f){
  FU v; v.f = f;
  unsigned r = v.u + 0x7fffu + ((v.u >> 16) & 1u);   // RNE
  return (unsigned short)(r >> 16);
}
__device__ __forceinline__ float bf2f(unsigned short s){
  FU v; v.u = ((unsigned)s) << 16; return v.f;
}
__device__ __forceinline__ bf16x8 zfrag(){
  U16x8 z;
  #pragma unroll
  for(int i=0;i<8;i++) z.s[i]=0;
  return z.v;
}
// 8 consecutive f32 -> split bf16 hi/lo fragments
__device__ __forceinline__ void split8(const float* p, bf16x8& hi, bf16x8& lo){
  float4 a = ((const float4*)p)[0];
  float4 b = ((const float4*)p)[1];
  float f[8] = {a.x,a.y,a.z,a.w,b.x,b.y,b.z,b.w};
  U16x8 h,l;
  #pragma unroll
  for(int i=0;i<8;i++){
    unsigned short hb = f2bf(f[i]);
    l.s[i] = f2bf(f[i] - bf2f(hb));
    h.s[i] = hb;
  }
  hi = h.v; lo = l.v;
}
// two uint4 (8 packed u32 words, bf16hi|bf16lo) -> hi/lo fragments
__device__ __forceinline__ void unpackg(uint4 A, uint4 B, bf16x8& hi, bf16x8& lo){
  unsigned wv[8] = {A.x,A.y,A.z,A.w,B.x,B.y,B.z,B.w};
  U16x8 h,l;
  #pragma unroll
  for(int j=0;j<8;j++){
    h.s[j] = (unsigned short)(wv[j] >> 16);
    l.s[j] = (unsigned short)(wv[j] & 0xffffu);
  }
  hi = h.v; lo = l.v;
}

#define MFMA __builtin_amdgcn_mfma_f32_16x16x32_bf16

// SELF-CONTAINED coherent load of both rows' k-quarter slices:
// 16 x dwordx4 sc1 + vmcnt(0) drain in ONE asm block (values ready at exit).
#define LD16W(G0,G1,G2,G3,G4,G5,G6,G7,G8,G9,Ga,Gb,Gc,Gd,Ge,Gf, B0, B1) \
  asm volatile( \
    "global_load_dwordx4 %0, %16, off sc1\n\t" \
    "global_load_dwordx4 %1, %16, off offset:16 sc1\n\t" \
    "global_load_dwordx4 %2, %16, off offset:128 sc1\n\t" \
    "global_load_dwordx4 %3, %16, off offset:144 sc1\n\t" \
    "global_load_dwordx4 %4, %16, off offset:256 sc1\n\t" \
    "global_load_dwordx4 %5, %16, off offset:272 sc1\n\t" \
    "global_load_dwordx4 %6, %16, off offset:384 sc1\n\t" \
    "global_load_dwordx4 %7, %16, off offset:400 sc1\n\t" \
    "global_load_dwordx4 %8, %17, off sc1\n\t" \
    "global_load_dwordx4 %9, %17, off offset:16 sc1\n\t" \
    "global_load_dwordx4 %10, %17, off offset:128 sc1\n\t" \
    "global_load_dwordx4 %11, %17, off offset:144 sc1\n\t" \
    "global_load_dwordx4 %12, %17, off offset:256 sc1\n\t" \
    "global_load_dwordx4 %13, %17, off offset:272 sc1\n\t" \
    "global_load_dwordx4 %14, %17, off offset:384 sc1\n\t" \
    "global_load_dwordx4 %15, %17, off offset:400 sc1\n\t" \
    "s_waitcnt vmcnt(0)" \
    : "=&v"(G0),"=&v"(G1),"=&v"(G2),"=&v"(G3),"=&v"(G4),"=&v"(G5),"=&v"(G6),"=&v"(G7), \
      "=&v"(G8),"=&v"(G9),"=&v"(Ga),"=&v"(Gb),"=&v"(Gc),"=&v"(Gd),"=&v"(Ge),"=&v"(Gf) \
    : "v"(B0), "v"(B1) : "memory")

__global__ __launch_bounds__(512, 2) void gru_scan(
    const float* __restrict__ x,  const float* __restrict__ Wm,
    const float* __restrict__ bW, const float* __restrict__ Um,
    const float* __restrict__ bU, float* __restrict__ out,
    unsigned* __restrict__ hbuf,  unsigned* __restrict__ flags)
{
  __shared__ f32x4 red [4][4][2][64];   // [q][mt][nt][lane] h-gate reduce (32 KB)
  __shared__ f32x4 red2[4][4][2][64];   // xg reduce (32 KB)
  __shared__ unsigned sctr;             // gate-wave arrival counter (monotone)

  const int tid  = threadIdx.x;
  const int u    = tid >> 6;        // wave 0..7
  const int q    = u >> 1;          // k-quarter
  const int m2   = u & 1;           // mt-pair: mt in {2*m2, 2*m2+1}
  const int lane = tid & 63;
  const int col  = lane & 15;
  const int lg   = lane >> 4;
  const int j0   = blockIdx.x * NJ;
  const int bid  = blockIdx.x;

  if(tid == 0) sctr = 0u;

  // ---- persistent U/W fragments for k-quarter q (split bf16, registers) ----
  bf16x8 BUhi[2][4], BUlo[2][4], BWhi[2][2], BWlo[2][2];
  #pragma unroll
  for(int nt=0; nt<2; nt++){
    int rl    = nt*16 + col;          // local row 0..31 (24 valid)
    int valid = rl < 24;
    int g     = rl >> 3, jj = rl & 7;
    int grow  = g*HH + j0 + jj;       // row in [3H]
    #pragma unroll
    for(int ks=0; ks<4; ks++){
      int kb = q*128 + ks*32 + lg*8;
      if(valid) split8(Um + (size_t)grow*HH + kb, BUhi[nt][ks], BUlo[nt][ks]);
      else { BUhi[nt][ks]=zfrag(); BUlo[nt][ks]=zfrag(); }
    }
    #pragma unroll
    for(int ks=0; ks<2; ks++){
      int kb = q*64 + ks*32 + lg*8;
      if(valid) split8(Wm + (size_t)grow*KIN + kb, BWhi[nt][ks], BWlo[nt][ks]);
      else { BWhi[nt][ks]=zfrag(); BWlo[nt][ks]=zfrag(); }
    }
  }

  // ---- biases for this lane's gate rows (gate waves u<4) ----
  float bsum0, bwn, bun;
  {
    int r0 = (col < 8) ? (j0 + col) : (HH + j0 + col - 8);
    bsum0 = bW[r0] + bU[r0];
    int rn = 2*HH + j0 + (col & 7);
    bwn = bW[rn]; bun = bU[rn];
  }

  float hreg[4] = {0.f,0.f,0.f,0.f};

  // ---- xg partials + cross-wave reduce (red2); gate waves get sums ----
  auto compute_xg = [&](int tt, f32x4 (&dst)[2]){
    f32x4 Cx[2][2];
    #pragma unroll
    for(int mi=0;mi<2;mi++){ Cx[mi][0]=(f32x4){0,0,0,0}; Cx[mi][1]=(f32x4){0,0,0,0}; }
    #pragma unroll
    for(int mi=0; mi<2; mi++){
      int mt = 2*m2 + mi, b = mt*16 + col;
      #pragma unroll
      for(int ks=0; ks<2; ks++){
        int kb = q*64 + ks*32 + lg*8;
        bf16x8 ah, al; split8(x + ((size_t)b*TT + tt)*KIN + kb, ah, al);
        #pragma unroll
        for(int nt=0; nt<2; nt++){
          Cx[mi][nt] = MFMA(ah, BWhi[nt][ks], Cx[mi][nt], 0,0,0);
          Cx[mi][nt] = MFMA(ah, BWlo[nt][ks], Cx[mi][nt], 0,0,0);
          Cx[mi][nt] = MFMA(al, BWhi[nt][ks], Cx[mi][nt], 0,0,0);
        }
      }
    }
    #pragma unroll
    for(int mi=0;mi<2;mi++)
      #pragma unroll
      for(int nt=0;nt<2;nt++)
        red2[q][2*m2+mi][nt][lane] = Cx[mi][nt];
    __syncthreads();
    if(u < 4){
      #pragma unroll
      for(int nt=0; nt<2; nt++)
        dst[nt] = red2[0][u][nt][lane] + red2[1][u][nt][lane]
                + red2[2][u][nt][lane] + red2[3][u][nt][lane];
    }
  };

  // ---- one GRU cell, index `cell` (0..1023) ----
  auto run_cell = [&](const unsigned* hb, unsigned* hw, int cell,
                      const f32x4 (&xgf)[2]){
    // 1) partial-order poll: wave q waits only on its 16 producer blocks
    {
      const unsigned tgt = (unsigned)cell;
      const unsigned fidx = (unsigned)(q*16) + (unsigned)(lane & 15);
      while(true){
        unsigned f = __hip_atomic_load(&flags[fidx], __ATOMIC_RELAXED,
                                       __HIP_MEMORY_SCOPE_AGENT);
        if(__all((int)(f >= tgt))) break;
        __builtin_amdgcn_s_sleep(2);
      }
      __builtin_amdgcn_sched_barrier(0);
    }

    // 2) load h once (both rows' quarter-slices, one latency exposure)
    int b0 = (2*m2+0)*16 + col, b1 = (2*m2+1)*16 + col;
    const void* a0 = (const char*)(hb + (size_t)b0*HH + q*128 + lg*8);
    const void* a1 = (const char*)(hb + (size_t)b1*HH + q*128 + lg*8);
    uint4 g00,g01,g02,g03,g04,g05,g06,g07,g10,g11,g12,g13,g14,g15,g16,g17;
    LD16W(g00,g01,g02,g03,g04,g05,g06,g07,
          g10,g11,g12,g13,g14,g15,g16,g17, a0, a1);
    __builtin_amdgcn_sched_barrier(0);

    // 3) MFMA h-matmul partials
    f32x4 Ch[2][2];
    #pragma unroll
    for(int mi=0;mi<2;mi++){ Ch[mi][0]=(f32x4){0,0,0,0}; Ch[mi][1]=(f32x4){0,0,0,0}; }
    {
      bf16x8 ah, al;
      unpackg(g00,g01,ah,al);
      #pragma unroll
      for(int nt=0;nt<2;nt++){ Ch[0][nt]=MFMA(ah,BUhi[nt][0],Ch[0][nt],0,0,0); Ch[0][nt]=MFMA(ah,BUlo[nt][0],Ch[0][nt],0,0,0); Ch[0][nt]=MFMA(al,BUhi[nt][0],Ch[0][nt],0,0,0); }
      unpackg(g02,g03,ah,al);
      #pragma unroll
      for(int nt=0;nt<2;nt++){ Ch[0][nt]=MFMA(ah,BUhi[nt][1],Ch[0][nt],0,0,0); Ch[0][nt]=MFMA(ah,BUlo[nt][1],Ch[0][nt],0,0,0); Ch[0][nt]=MFMA(al,BUhi[nt][1],Ch[0][nt],0,0,0); }
      unpackg(g04,g05,ah,al);
      #pragma unroll
      for(int nt=0;nt<2;nt++){ Ch[0][nt]=MFMA(ah,BUhi[nt][2],Ch[0][nt],0,0,0); Ch[0][nt]=MFMA(ah,BUlo[nt][2],Ch[0][nt],0,0,0); Ch[0][nt]=MFMA(al,BUhi[nt][2],Ch[0][nt],0,0,0); }
      unpackg(g06,g07,ah,al);
      #pragma unroll
      for(int nt=0;nt<2;nt++){ Ch[0][nt]=MFMA(ah,BUhi[nt][3],Ch[0][nt],0,0,0); Ch[0][nt]=MFMA(ah,BUlo[nt][3],Ch[0][nt],0,0,0); Ch[0][nt]=MFMA(al,BUhi[nt][3],Ch[0][nt],0,0,0); }
      unpackg(g10,g11,ah,al);
      #pragma unroll
      for(int nt=0;nt<2;nt++){ Ch[1][nt]=MFMA(ah,BUhi[nt][0],Ch[1][nt],0,0,0); Ch[1][nt]=MFMA(ah,BUlo[nt][0],Ch[1][nt],0,0,0); Ch[1][nt]=MFMA(al,BUhi[nt][0],Ch[1][nt],0,0,0); }
      unpackg(g12,g13,ah,al);
      #pragma unroll
      for(int nt=0;nt<2;nt++){ Ch[1][nt]=MFMA(ah,BUhi[nt][1],Ch[1][nt],0,0,0); Ch[1][nt]=MFMA(ah,BUlo[nt][1],Ch[1][nt],0,0,0); Ch[1][nt]=MFMA(al,BUhi[nt][1],Ch[1][nt],0,0,0); }
      unpackg(g14,g15,ah,al);
      #pragma unroll
      for(int nt=0;nt<2;nt++){ Ch[1][nt]=MFMA(ah,BUhi[nt][2],Ch[1][nt],0,0,0); Ch[1][nt]=MFMA(ah,BUlo[nt][2],Ch[1][nt],0,0,0); Ch[1][nt]=MFMA(al,BUhi[nt][2],Ch[1][nt],0,0,0); }
      unpackg(g16,g17,ah,al);
      #pragma unroll
      for(int nt=0;nt<2;nt++){ Ch[1][nt]=MFMA(ah,BUhi[nt][3],Ch[1][nt],0,0,0); Ch[1][nt]=MFMA(ah,BUlo[nt][3],Ch[1][nt],0,0,0); Ch[1][nt]=MFMA(al,BUhi[nt][3],Ch[1][nt],0,0,0); }
    }
    #pragma unroll
    for(int mi=0;mi<2;mi++)
      #pragma unroll
      for(int nt=0;nt<2;nt++)
        red[q][2*m2+mi][nt][lane] = Ch[mi][nt];
    __syncthreads();

    // 4) gate waves: reduce, gates, h-stores
    if(u < 4){
      const int w = u;
      f32x4 hgf[2];
      #pragma unroll
      for(int nt=0; nt<2; nt++)
        hgf[nt] = red[0][w][nt][lane] + red[1][w][nt][lane]
                + red[2][w][nt][lane] + red[3][w][nt][lane];
      float p0[4], p0s[4];
      #pragma unroll
      for(int r=0;r<4;r++) p0[r] = xgf[0][r] + hgf[0][r] + bsum0;
      #pragma unroll
      for(int r=0;r<4;r++) p0s[r] = __shfl_xor(p0[r], 8, 64);
      float hn4[4];
      if(col < 8){
        #pragma unroll
        for(int r=0;r<4;r++){
          int b = w*16 + lg*4 + r;
          float rg = __builtin_amdgcn_rcpf(1.f + __expf(-p0[r]));
          float ug = __builtin_amdgcn_rcpf(1.f + __expf(-p0s[r]));
          float hn = hgf[1][r] + bun;
          float z  = xgf[1][r] + bwn + rg*hn;
          z = fminf(fmaxf(z, -15.f), 15.f);
          float e  = __expf(2.f*z);
          float nn = (e - 1.f) * __builtin_amdgcn_rcpf(e + 1.f);   // tanh(z)
          float hnew = ug*hreg[r] + (1.f - ug)*nn;
          hreg[r] = hnew;
          hn4[r]  = hnew;
          unsigned short h16 = f2bf(hnew);
          unsigned short l16 = f2bf(hnew - bf2f(h16));
          __hip_atomic_store(&hw[(size_t)b*HH + j0 + col],
                             ((unsigned)h16 << 16) | (unsigned)l16,
                             __ATOMIC_RELAXED, __HIP_MEMORY_SCOPE_AGENT);
        }
      }
      // 5) release the other waves into the next cell NOW
      __builtin_amdgcn_s_barrier();
      // 6) drain h-stores to LLC, then publish flag (last gate wave)
      asm volatile("s_waitcnt vmcnt(0)" ::: "memory");
      if(lane == 0){
        unsigned old = __hip_atomic_fetch_add(&sctr, 1u, __ATOMIC_RELAXED,
                                              __HIP_MEMORY_SCOPE_WORKGROUP);
        if(old == 4u*(unsigned)cell + 3u)
          __hip_atomic_store(&flags[bid], (unsigned)cell + 1u,
                             __ATOMIC_RELAXED, __HIP_MEMORY_SCOPE_AGENT);
      }
      // 7) out-stores off the critical path
      if(col < 8){
        #pragma unroll
        for(int r=0;r<4;r++){
          int b = w*16 + lg*4 + r;
          out[((size_t)cell*BB + b)*HH + j0 + col] = hn4[r];
        }
      }
    } else {
      __builtin_amdgcn_s_barrier();
    }
  };

  unsigned* hb0 = hbuf;
  unsigned* hb1 = hbuf + (size_t)BB*HH;

  f32x4 xgf[2] = {(f32x4){0,0,0,0},(f32x4){0,0,0,0}};
  f32x4 xgn[2] = {(f32x4){0,0,0,0},(f32x4){0,0,0,0}};
  compute_xg(0, xgf);

  for(int t=0; t<TT; t++){
    run_cell(hb0, hb1, 2*t, xgf);      // layer 0: read buf0, write buf1
    if(t+1 < TT) compute_xg(t+1, xgn); // overlap with producers' drain/flag
    run_cell(hb1, hb0, 2*t+1, xgf);    // layer 1: read buf1, write buf0
    xgf[0] = xgn[0]; xgf[1] = xgn[1];
  }
}

extern "C" void kernel_launch(void* const* d_in, const int* in_sizes, int n_in,
                              void* d_out, int out_size, void* d_ws, size_t ws_size,
                              hipStream_t stream) {
  const float* x  = (const float*)d_in[0];
  const float* Wm = (const float*)d_in[1];
  const float* bW = (const float*)d_in[2];
  const float* Um = (const float*)d_in[3];
  const float* bU = (const float*)d_in[4];
  float* out = (float*)d_out;

  // ws layout: hbuf[2][64][512] u32 (256 KB) + flags[64] u32
  unsigned* hbuf  = (unsigned*)d_ws;
  unsigned* flags = (unsigned*)((char*)d_ws + 2*BB*HH*sizeof(unsigned));
  (void)hipMemsetAsync(d_ws, 0, 2*BB*HH*sizeof(unsigned) + 256, stream);

  gru_scan<<<NBLK, 512, 0, stream>>>(x, Wm, bW, Um, bU, out, hbuf, flags);
}